// Round 11
// baseline (948.487 us; speedup 1.0000x reference)
//
#include <hip/hip_runtime.h>
#include <cstdint>
#include <cstddef>

// Problem constants
#define LSEQ 2048
#define BB   32
#define DD   1024
#define NLAYERS 4
#define MM   (LSEQ*BB)      // 65536 rows
#define BD   (BB*DD)        // 32768
#define CHUNK 32
#define NCHUNK (LSEQ/CHUNK) // 64

typedef _Float16 f16;
typedef __attribute__((ext_vector_type(8))) _Float16 f16x8;
typedef __attribute__((ext_vector_type(4))) float f32x4;

// ---------------- scan: h[t] = a*h[t-1] + x[t], a = exp(A_log[d]) ----------------

__global__ void scan_pass1(const float* __restrict__ x, const float* __restrict__ Alog,
                           f16* __restrict__ h, float* __restrict__ carry) {
    int tid = blockIdx.x * blockDim.x + threadIdx.x;   // 2M threads
    int bd  = tid & (BD - 1);
    int c   = tid >> 15;                               // chunk id
    float a = expf(Alog[bd & (DD - 1)]);
    size_t base = (size_t)c * CHUNK * BD + bd;
    float hv = 0.f;
#pragma unroll
    for (int i = 0; i < CHUNK; ++i) {
        hv = a * hv + x[base + (size_t)i * BD];
        h[base + (size_t)i * BD] = (f16)hv;
    }
    carry[c * BD + bd] = hv;
}

__global__ void scan_pass2(const float* __restrict__ Alog, float* __restrict__ carry) {
    int bd = blockIdx.x * blockDim.x + threadIdx.x;    // 32768 threads
    float d32 = expf((float)CHUNK * Alog[bd & (DD - 1)]);  // a^CHUNK
    float cin = 0.f;
    for (int c = 0; c < NCHUNK; ++c) {
        float co = carry[c * BD + bd];
        carry[c * BD + bd] = cin;       // exclusive carry-in
        cin = d32 * cin + co;
    }
}

__global__ void scan_pass3(const float* __restrict__ Alog, const float* __restrict__ carry,
                           f16* __restrict__ h) {
    int tid = blockIdx.x * blockDim.x + threadIdx.x;
    int bd  = tid & (BD - 1);
    int c   = tid >> 15;
    float a   = expf(Alog[bd & (DD - 1)]);
    float cin = carry[c * BD + bd];
    size_t base = (size_t)c * CHUNK * BD + bd;
    float p = a;
#pragma unroll
    for (int i = 0; i < CHUNK; ++i) {
        size_t idx = base + (size_t)i * BD;
        float hv = (float)h[idx] + p * cin;
        h[idx] = (f16)hv;
        p *= a;
    }
}

// ---------------- fp32 -> fp16 weight conversion ----------------

__global__ void cvt_w(const float* __restrict__ w, f16* __restrict__ o, int n) {
    int i = (blockIdx.x * blockDim.x + threadIdx.x) * 4;
    if (i + 3 < n) {
        float4 v = *(const float4*)&w[i];
        o[i + 0] = (f16)v.x; o[i + 1] = (f16)v.y;
        o[i + 2] = (f16)v.z; o[i + 3] = (f16)v.w;
    }
}

// ---------------- GEMM + bias + tanh: m97 structure (128x128, TLP overlap) ----------------
// C[m][n] = tanh(sum_k A[m][k]*W[n][k] + b[n])
// Tile 128x128, BK=32, 32 K-steps, SINGLE-buffered LDS (16 KiB total).
// 256 thr = 4 waves (2Mx2N), wave tile 64x64, mfma 16x16x32 f16, acc 4x4
// (64 AGPR). Small LDS + small acc -> ~12 waves/CU (3 blocks/CU): the
// vmcnt(0) staging stall of one block overlaps other blocks' MFMA clusters
// (m114 TLP mechanism; m103: 128^2=912 TF beats 256^2=792 at this structure).
// Per K-step:  BAR            [prev tile's reads all consumed]
//              stage tile kt  [4x gload_lds16/thread]
//              vmcnt(0); BAR  [tile visible]
//              8 ds_read_b128 -> 16 MFMA (setprio)
// T2: chunk ^= (row>>1)&3 swizzle (2-way residual = free), inverse-swz
//     global source, linear gload_lds dest (rule #21).
// T1: XCD-chunked bijective block swizzle (nwg=4096, %8==0); N-fastest within
//     chunk -> A-panel (256 KB) loaded once per XCD L2, W (2 MB) L2-resident.
// FUSED-HEAD mode (pbuf != nullptr, layer 4): dot tanh-output rows with hw,
// shfl-reduce over 16 fr-lanes, cross-wave sum via LDS, write per-(row,
// N-block) partials; head_final sums 8 partials + bias.

#define BM 128
#define BN 128
#define BK 32
#define KK 1024
#define NN 1024
#define NKT (KK / BK)        // 32 K-steps

__device__ __forceinline__ void gload_lds16(const void* g, void* l) {
    __builtin_amdgcn_global_load_lds((const __attribute__((address_space(1))) unsigned int*)g,
                                     (__attribute__((address_space(3))) unsigned int*)l,
                                     16, 0, 0);
}

// swizzled fragment read from a [128][32] f16 tile
__device__ __forceinline__ f16x8 rd(const f16* base, int row, int chunk) {
    int c = chunk ^ ((row >> 1) & 3);
    return *(const f16x8*)(base + row * 32 + c * 8);
}

__device__ __forceinline__ float tanh_fast(float z) {
    float e = __expf(2.f * z);
    return 1.f - 2.f / (e + 1.f);
}

#define BAR() do { __builtin_amdgcn_sched_barrier(0); __builtin_amdgcn_s_barrier(); \
                   __builtin_amdgcn_sched_barrier(0); } while (0)

__global__ __launch_bounds__(256) void gemm_tanh(const f16* __restrict__ A,
                                                 const f16* __restrict__ W,
                                                 const float* __restrict__ bias,
                                                 f16* __restrict__ C,
                                                 const float* __restrict__ hw,
                                                 float* __restrict__ pbuf) {
    __shared__ f16 As[BM * BK];   // 8 KiB
    __shared__ f16 Bs[BN * BK];   // 8 KiB

    const int tid  = threadIdx.x;
    const int lane = tid & 63;
    const int wid  = tid >> 6;        // 0..3
    const int wr   = wid >> 1;        // 0..1  (M half)
    const int wc   = wid & 1;         // 0..1  (N half)

    // T1: XCD-chunked bijective swizzle (nwg=4096, %8==0)
    const int cpx = gridDim.x >> 3;
    const int lin = ((int)blockIdx.x & 7) * cpx + ((int)blockIdx.x >> 3);
    const int tm  = (lin >> 3) * BM;          // 512 M-panels, slow within XCD
    const int tn  = (lin & 7) * BN;           // 8 N-tiles, fast within XCD

    const f16* Ab = A + (size_t)tm * KK;
    const f16* Wb = W + (size_t)tn * KK;

    const int fr = lane & 15;         // fragment row within 16
    const int fc = lane >> 4;         // 16B k-chunk 0..3

    f32x4 acc[4][4];
#pragma unroll
    for (int i = 0; i < 4; ++i)
#pragma unroll
        for (int j = 0; j < 4; ++j)
            acc[i][j] = (f32x4){0.f, 0.f, 0.f, 0.f};

    const int arow = wr * 64 + fr;    // + mi*16
    const int brow = wc * 64 + fr;    // + ni*16

    // stage addressing: 512 16B-slots per matrix, 2 slots/thread each
    const int s0 = tid, s1 = tid + 256;
    const int r0s = s0 >> 2, c0s = (s0 & 3) ^ ((r0s >> 1) & 3);
    const int r1s = s1 >> 2, c1s = (s1 & 3) ^ ((r1s >> 1) & 3);

    for (int kt = 0; kt < NKT; ++kt) {
        BAR();                        // prev tile fully consumed block-wide
        const size_t ko = (size_t)kt * BK;
        gload_lds16(Ab + (size_t)r0s * KK + ko + c0s * 8, (f16*)As + s0 * 8);
        gload_lds16(Ab + (size_t)r1s * KK + ko + c1s * 8, (f16*)As + s1 * 8);
        gload_lds16(Wb + (size_t)r0s * KK + ko + c0s * 8, (f16*)Bs + s0 * 8);
        gload_lds16(Wb + (size_t)r1s * KK + ko + c1s * 8, (f16*)Bs + s1 * 8);
        asm volatile("s_waitcnt vmcnt(0)" ::: "memory");
        BAR();                        // tile kt visible

        f16x8 a[4], b[4];
#pragma unroll
        for (int mi = 0; mi < 4; ++mi) a[mi] = rd(As, arow + mi * 16, fc);
#pragma unroll
        for (int ni = 0; ni < 4; ++ni) b[ni] = rd(Bs, brow + ni * 16, fc);
        __builtin_amdgcn_s_setprio(1);
#pragma unroll
        for (int mi = 0; mi < 4; ++mi)
#pragma unroll
            for (int ni = 0; ni < 4; ++ni)
                acc[mi][ni] = __builtin_amdgcn_mfma_f32_16x16x32_f16(a[mi], b[ni], acc[mi][ni], 0, 0, 0);
        __builtin_amdgcn_s_setprio(0);
    }

    if (pbuf == nullptr) {
        // epilogue: bias + fast tanh, store f16 (mi outer: row-major order)
#pragma unroll
        for (int mi = 0; mi < 4; ++mi) {
            const int r0 = tm + wr * 64 + mi * 16 + (fc << 2);
#pragma unroll
            for (int ni = 0; ni < 4; ++ni) {
                const int c = tn + wc * 64 + ni * 16 + fr;
                const float bv = bias[c];
#pragma unroll
                for (int q = 0; q < 4; ++q) {
                    float z = acc[mi][ni][q] + bv;
                    C[(size_t)(r0 + q) * NN + c] = (f16)tanh_fast(z);
                }
            }
        }
    } else {
        // fused-head epilogue: partial[row, nb] = sum over this block's 128
        // columns of tanh(acc + bias[c]) * hw[c].
        BAR();                                // K-loop done; As reusable
        float* red = (float*)&As[0];          // [128 rows][2 wc] floats = 1 KB
#pragma unroll
        for (int mi = 0; mi < 4; ++mi) {
            float s[4] = {0.f, 0.f, 0.f, 0.f};
#pragma unroll
            for (int ni = 0; ni < 4; ++ni) {
                const int c = tn + wc * 64 + ni * 16 + fr;
                const float bv = bias[c];
                const float wv = hw[c];
#pragma unroll
                for (int q = 0; q < 4; ++q)
                    s[q] += tanh_fast(acc[mi][ni][q] + bv) * wv;
            }
#pragma unroll
            for (int q = 0; q < 4; ++q) {
#pragma unroll
                for (int o = 1; o < 16; o <<= 1)
                    s[q] += __shfl_xor(s[q], o, 64);
            }
            if (fr == 0) {
                const int rloc = wr * 64 + mi * 16 + (fc << 2);
#pragma unroll
                for (int q = 0; q < 4; ++q)
                    red[(rloc + q) * 2 + wc] = s[q];
            }
        }
        __syncthreads();
        if (tid < 128) {
            const float2 v = *(const float2*)&red[tid * 2];
            pbuf[(size_t)(tm + tid) * 8 + (tn >> 7)] = v.x + v.y;
        }
    }
}

// ---------------- head final: out[m] = sum_nb partial[m][nb] + hb ----------------

__global__ void head_final(const float* __restrict__ pbuf, const float* __restrict__ hb,
                           float* __restrict__ out) {
    const int m = blockIdx.x * blockDim.x + threadIdx.x;
    const float4 v0 = *(const float4*)&pbuf[(size_t)m * 8];
    const float4 v1 = *(const float4*)&pbuf[(size_t)m * 8 + 4];
    out[m] = v0.x + v0.y + v0.z + v0.w + v1.x + v1.y + v1.z + v1.w + hb[0];
}

// ---------------- launch ----------------

extern "C" void kernel_launch(void* const* d_in, const int* in_sizes, int n_in,
                              void* d_out, int out_size, void* d_ws, size_t ws_size,
                              hipStream_t stream) {
    const float* x    = (const float*)d_in[0];
    const float* Alog = (const float*)d_in[1];
    const float* Wls  = (const float*)d_in[2];
    const float* bls  = (const float*)d_in[3];
    const float* hw   = (const float*)d_in[4];
    const float* hb   = (const float*)d_in[5];
    float* out = (float*)d_out;

    char* ws = (char*)d_ws;
    const size_t hbytes = (size_t)MM * DD * sizeof(f16);   // 128 MiB
    f16* h0 = (f16*)ws;
    f16* h1 = (f16*)(ws + hbytes);
    char* scratch = ws + 2 * hbytes;
    float* carry = (float*)scratch;                         // 8 MiB, scan phase only
    f16*   wf    = (f16*)scratch;                           // 8 MiB, reused after scan
    float* pbuf  = (float*)h0;                              // 2 MiB, layer-4 partials
                                                            // (h0 free during layer 4)

    // 1. scan (chunked, 3 passes)
    scan_pass1<<<(NCHUNK * BD) / 256, 256, 0, stream>>>(x, Alog, h0, carry);
    scan_pass2<<<BD / 256, 256, 0, stream>>>(Alog, carry);
    scan_pass3<<<(NCHUNK * BD) / 256, 256, 0, stream>>>(Alog, carry, h0);

    // 2. weights fp32 -> fp16 (reuses carry region; stream-ordered after pass3)
    cvt_w<<<(NLAYERS * DD * DD / 4) / 256, 256, 0, stream>>>(Wls, wf, NLAYERS * DD * DD);

    // 3. four layers, ping-pong; layer 4 fuses the head dot-product
    dim3 grid((MM / BM) * (NN / BN)), blk(256);
    gemm_tanh<<<grid, blk, 0, stream>>>(h0, wf + 0 * (DD * DD), bls + 0 * DD, h1, nullptr, nullptr);
    gemm_tanh<<<grid, blk, 0, stream>>>(h1, wf + 1 * (DD * DD), bls + 1 * DD, h0, nullptr, nullptr);
    gemm_tanh<<<grid, blk, 0, stream>>>(h0, wf + 2 * (DD * DD), bls + 2 * DD, h1, nullptr, nullptr);
    gemm_tanh<<<grid, blk, 0, stream>>>(h1, wf + 3 * (DD * DD), bls + 3 * DD, nullptr, hw, pbuf);

    // 4. head: sum the 8 per-N-block partials + bias
    head_final<<<MM / 256, 256, 0, stream>>>(pbuf, hb, out);
}

// Round 12
// 789.124 us; speedup vs baseline: 1.2019x; 1.2019x over previous
//
#include <hip/hip_runtime.h>
#include <cstdint>
#include <cstddef>

// Problem constants
#define LSEQ 2048
#define BB   32
#define DD   1024
#define NLAYERS 4
#define MM   (LSEQ*BB)      // 65536 rows
#define BD   (BB*DD)        // 32768
#define CHUNK 32
#define NCHUNK (LSEQ/CHUNK) // 64

typedef _Float16 f16;
typedef __attribute__((ext_vector_type(8))) _Float16 f16x8;
typedef __attribute__((ext_vector_type(4))) float f32x4;

// ---------------- scan: h[t] = a*h[t-1] + x[t], a = exp(A_log[d]) ----------------

__global__ void scan_pass1(const float* __restrict__ x, const float* __restrict__ Alog,
                           f16* __restrict__ h, float* __restrict__ carry) {
    int tid = blockIdx.x * blockDim.x + threadIdx.x;   // 2M threads
    int bd  = tid & (BD - 1);
    int c   = tid >> 15;                               // chunk id
    float a = expf(Alog[bd & (DD - 1)]);
    size_t base = (size_t)c * CHUNK * BD + bd;
    float hv = 0.f;
#pragma unroll
    for (int i = 0; i < CHUNK; ++i) {
        hv = a * hv + x[base + (size_t)i * BD];
        h[base + (size_t)i * BD] = (f16)hv;
    }
    carry[c * BD + bd] = hv;
}

__global__ void scan_pass2(const float* __restrict__ Alog, float* __restrict__ carry) {
    int bd = blockIdx.x * blockDim.x + threadIdx.x;    // 32768 threads
    float d32 = expf((float)CHUNK * Alog[bd & (DD - 1)]);  // a^CHUNK
    float cin = 0.f;
    for (int c = 0; c < NCHUNK; ++c) {
        float co = carry[c * BD + bd];
        carry[c * BD + bd] = cin;       // exclusive carry-in
        cin = d32 * cin + co;
    }
}

__global__ void scan_pass3(const float* __restrict__ Alog, const float* __restrict__ carry,
                           f16* __restrict__ h) {
    int tid = blockIdx.x * blockDim.x + threadIdx.x;
    int bd  = tid & (BD - 1);
    int c   = tid >> 15;
    float a   = expf(Alog[bd & (DD - 1)]);
    float cin = carry[c * BD + bd];
    size_t base = (size_t)c * CHUNK * BD + bd;
    float p = a;
#pragma unroll
    for (int i = 0; i < CHUNK; ++i) {
        size_t idx = base + (size_t)i * BD;
        float hv = (float)h[idx] + p * cin;
        h[idx] = (f16)hv;
        p *= a;
    }
}

// ---------------- fp32 -> fp16 weight conversion ----------------

__global__ void cvt_w(const float* __restrict__ w, f16* __restrict__ o, int n) {
    int i = (blockIdx.x * blockDim.x + threadIdx.x) * 4;
    if (i + 3 < n) {
        float4 v = *(const float4*)&w[i];
        o[i + 0] = (f16)v.x; o[i + 1] = (f16)v.y;
        o[i + 2] = (f16)v.z; o[i + 3] = (f16)v.w;
    }
}

// ---------------- GEMM + bias + tanh: R7 schedule at 128x128 (2 blocks/CU) ----------------
// C[m][n] = tanh(sum_k A[m][k]*W[n][k] + b[n])
// Tile 128x128, BK=64, 16 K-tiles, double-buffered LDS (64 KiB total ->
// 2 blocks/CU via __launch_bounds__(256,2)). 256 thr = 4 waves (2Mx2N),
// wave tile 64x64, mfma 16x16x32 f16, acc 4x4 (64 AGPR, ~110 VGPR).
// R7 schedule (measured best at 256^2) scaled down; cross-BLOCK TLP now
// covers barrier/stage windows (m114: co-resident block's MFMA overlaps):
//   read16(cur)  [k0 group then k1 group, NO barrier after]
//   MFMA16(k0)   <- compiler emits counted lgkmcnt: k1 reads drain under it
//   lgkm0; BAR1  <- cur fully read block-wide, safe to overwrite
//   stage(t+2 -> cur buf); MFMA16(k1)  <- gload issue overlaps cluster
//   vmcnt(8); BAR2  <- t+1 landed & published (vmcnt(0) only at tail)
// T2: chunk ^= (row&7) swizzle, inverse-swz global src, linear gload_lds dest.
// T5: setprio around MFMA clusters. T1: XCD-chunked block swizzle (nwg=4096,
// %8==0), N-fastest within chunk (A-panel L2-resident per XCD).
// FUSED-HEAD mode (pbuf != nullptr, layer 4): dot tanh rows with hw,
// shfl-reduce over 16 fr-lanes, cross-wave LDS sum, per-(row,N-block)
// partials; head_final sums 8 partials + bias.

#define BM 128
#define BN 128
#define BK 64
#define KK 1024
#define NN 1024
#define NKTILE (KK / BK)     // 16

__device__ __forceinline__ void gload_lds16(const void* g, void* l) {
    __builtin_amdgcn_global_load_lds((const __attribute__((address_space(1))) unsigned int*)g,
                                     (__attribute__((address_space(3))) unsigned int*)l,
                                     16, 0, 0);
}

// stage one 128x64 f16 matrix tile (16 KiB): 1024 slots, 4 loads/thread.
__device__ __forceinline__ void stage_mat(const f16* __restrict__ gbase, f16* region, int tid) {
#pragma unroll
    for (int j = 0; j < 4; ++j) {
        int s = tid + j * 256;               // 16B slot 0..1023
        int r = s >> 3;                      // row 0..127 (8 slots/row)
        int c = (s & 7) ^ (r & 7);           // inverse-swizzled source chunk
        gload_lds16(gbase + (size_t)r * KK + c * 8, region + (size_t)s * 8);
    }
}

// stage a full K-tile (A and W): 8 loads/thread
__device__ __forceinline__ void stage_tile(const f16* __restrict__ gA, const f16* __restrict__ gW,
                                           f16* As, f16* Bs, int tid) {
    stage_mat(gA, As, tid);
    stage_mat(gW, Bs, tid);
}

// swizzled fragment read from a [128][64] f16 tile
__device__ __forceinline__ f16x8 rd(const f16* base, int row, int chunk) {
    int c = chunk ^ (row & 7);
    return *(const f16x8*)(base + row * 64 + c * 8);
}

__device__ __forceinline__ void read8(const f16* Abase, const f16* Bbase,
                                      int arow, int brow, int kc,
                                      f16x8 a[4], f16x8 b[4]) {
#pragma unroll
    for (int m = 0; m < 4; ++m) a[m] = rd(Abase, arow + m * 16, kc);
#pragma unroll
    for (int n = 0; n < 4; ++n) b[n] = rd(Bbase, brow + n * 16, kc);
}

__device__ __forceinline__ float tanh_fast(float z) {
    float e = __expf(2.f * z);
    return 1.f - 2.f / (e + 1.f);
}

#define BAR() do { __builtin_amdgcn_sched_barrier(0); __builtin_amdgcn_s_barrier(); \
                   __builtin_amdgcn_sched_barrier(0); } while (0)

#define MFMA16(av, bv) do {                                                     \
    __builtin_amdgcn_s_setprio(1);                                              \
    _Pragma("unroll")                                                           \
    for (int m = 0; m < 4; ++m)                                                 \
        _Pragma("unroll")                                                       \
        for (int n = 0; n < 4; ++n)                                             \
            acc[m][n] = __builtin_amdgcn_mfma_f32_16x16x32_f16(av[m], bv[n],    \
                                                               acc[m][n], 0, 0, 0); \
    __builtin_amdgcn_s_setprio(0);                                              \
} while (0)

__global__ __launch_bounds__(256, 2) void gemm_tanh(const f16* __restrict__ A,
                                                    const f16* __restrict__ W,
                                                    const float* __restrict__ bias,
                                                    f16* __restrict__ C,
                                                    const float* __restrict__ hw,
                                                    float* __restrict__ pbuf) {
    __shared__ f16 As[2][BM * BK];   // 2 x 16 KiB
    __shared__ f16 Bs[2][BN * BK];   // 2 x 16 KiB

    const int tid  = threadIdx.x;
    const int lane = tid & 63;
    const int wid  = tid >> 6;        // 0..3
    const int wr   = wid >> 1;        // 0..1  (M half)
    const int wc   = wid & 1;         // 0..1  (N half)

    // T1: XCD-chunked bijective swizzle (nwg=4096, %8==0)
    const int cpx = gridDim.x >> 3;
    const int lin = ((int)blockIdx.x & 7) * cpx + ((int)blockIdx.x >> 3);
    const int tm  = (lin >> 3) * BM;          // 512 M-panels, slow within XCD
    const int tn  = (lin & 7) * BN;           // 8 N-tiles, fast within XCD

    const f16* Ab = A + (size_t)tm * KK;
    const f16* Wb = W + (size_t)tn * KK;

    const int fr = lane & 15;         // fragment row within 16
    const int fc = lane >> 4;         // 16B k-chunk 0..3 within a 32-k step

    f32x4 acc[4][4];
#pragma unroll
    for (int i = 0; i < 4; ++i)
#pragma unroll
        for (int j = 0; j < 4; ++j)
            acc[i][j] = (f32x4){0.f, 0.f, 0.f, 0.f};

    // prologue: tile0 -> buf0, tile1 -> buf1 (16 loads/thread in flight)
    stage_tile(Ab,      Wb,      &As[0][0], &Bs[0][0], tid);
    stage_tile(Ab + 64, Wb + 64, &As[1][0], &Bs[1][0], tid);
    asm volatile("s_waitcnt vmcnt(8)" ::: "memory");   // tile0 landed
    BAR();

    const int arow = wr * 64 + fr;
    const int brow = wc * 64 + fr;

    for (int it = 0; it < NKTILE / 2; ++it) {
        const bool pf = (it + 1 < NKTILE / 2);
        f16x8 a0[4], b0[4], a1[4], b1[4];

        // ======== sub A: K-tile t=2it in buf0 ========
        read8(&As[0][0], &Bs[0][0], arow, brow, fc,     a0, b0);   // k0 group
        read8(&As[0][0], &Bs[0][0], arow, brow, 4 + fc, a1, b1);   // k1 group
        MFMA16(a0, b0);                                 // k1 reads drain under this
        asm volatile("s_waitcnt lgkmcnt(0)" ::: "memory");   // all buf0 reads retired
        BAR();
        if (pf) stage_tile(Ab + (size_t)(2 * it + 2) * BK, Wb + (size_t)(2 * it + 2) * BK,
                           &As[0][0], &Bs[0][0], tid);       // t+2 -> buf0
        MFMA16(a1, b1);                                 // gload issue overlaps
        if (pf) asm volatile("s_waitcnt vmcnt(8)" ::: "memory");   // tile t+1 landed
        else    asm volatile("s_waitcnt vmcnt(0)" ::: "memory");   // t=14: tile15 landed
        BAR();                                          // publish buf1

        // ======== sub B: K-tile t=2it+1 in buf1 ========
        read8(&As[1][0], &Bs[1][0], arow, brow, fc,     a0, b0);
        read8(&As[1][0], &Bs[1][0], arow, brow, 4 + fc, a1, b1);
        MFMA16(a0, b0);
        asm volatile("s_waitcnt lgkmcnt(0)" ::: "memory");   // all buf1 reads retired
        BAR();
        if (pf) stage_tile(Ab + (size_t)(2 * it + 3) * BK, Wb + (size_t)(2 * it + 3) * BK,
                           &As[1][0], &Bs[1][0], tid);       // t+2 -> buf1
        MFMA16(a1, b1);
        if (pf) asm volatile("s_waitcnt vmcnt(8)" ::: "memory");   // tile t+1 landed
        BAR();                                          // publish buf0
    }

    if (pbuf == nullptr) {
        // epilogue: bias + fast tanh, store f16 (mi outer: row-major order)
#pragma unroll
        for (int mi = 0; mi < 4; ++mi) {
            const int r0 = tm + wr * 64 + mi * 16 + (fc << 2);
#pragma unroll
            for (int ni = 0; ni < 4; ++ni) {
                const int c = tn + wc * 64 + ni * 16 + fr;
                const float bv = bias[c];
#pragma unroll
                for (int q = 0; q < 4; ++q) {
                    float z = acc[mi][ni][q] + bv;
                    C[(size_t)(r0 + q) * NN + c] = (f16)tanh_fast(z);
                }
            }
        }
    } else {
        // fused-head epilogue: partial[row, nb] = sum over this block's 128
        // columns of tanh(acc + bias[c]) * hw[c].
        BAR();                                // K-loop done; As reusable
        float* red = (float*)&As[0][0];       // [128 rows][2 wc] floats = 1 KB
#pragma unroll
        for (int mi = 0; mi < 4; ++mi) {
            float s[4] = {0.f, 0.f, 0.f, 0.f};
#pragma unroll
            for (int ni = 0; ni < 4; ++ni) {
                const int c = tn + wc * 64 + ni * 16 + fr;
                const float bv = bias[c];
                const float wv = hw[c];
#pragma unroll
                for (int q = 0; q < 4; ++q)
                    s[q] += tanh_fast(acc[mi][ni][q] + bv) * wv;
            }
#pragma unroll
            for (int q = 0; q < 4; ++q) {
#pragma unroll
                for (int o = 1; o < 16; o <<= 1)
                    s[q] += __shfl_xor(s[q], o, 64);
            }
            if (fr == 0) {
                const int rloc = wr * 64 + mi * 16 + (fc << 2);
#pragma unroll
                for (int q = 0; q < 4; ++q)
                    red[(rloc + q) * 2 + wc] = s[q];
            }
        }
        __syncthreads();
        if (tid < 128) {
            const float2 v = *(const float2*)&red[tid * 2];
            pbuf[(size_t)(tm + tid) * 8 + (tn >> 7)] = v.x + v.y;
        }
    }
}

// ---------------- head final: out[m] = sum_nb partial[m][nb] + hb ----------------

__global__ void head_final(const float* __restrict__ pbuf, const float* __restrict__ hb,
                           float* __restrict__ out) {
    const int m = blockIdx.x * blockDim.x + threadIdx.x;
    const float4 v0 = *(const float4*)&pbuf[(size_t)m * 8];
    const float4 v1 = *(const float4*)&pbuf[(size_t)m * 8 + 4];
    out[m] = v0.x + v0.y + v0.z + v0.w + v1.x + v1.y + v1.z + v1.w + hb[0];
}

// ---------------- launch ----------------

extern "C" void kernel_launch(void* const* d_in, const int* in_sizes, int n_in,
                              void* d_out, int out_size, void* d_ws, size_t ws_size,
                              hipStream_t stream) {
    const float* x    = (const float*)d_in[0];
    const float* Alog = (const float*)d_in[1];
    const float* Wls  = (const float*)d_in[2];
    const float* bls  = (const float*)d_in[3];
    const float* hw   = (const float*)d_in[4];
    const float* hb   = (const float*)d_in[5];
    float* out = (float*)d_out;

    char* ws = (char*)d_ws;
    const size_t hbytes = (size_t)MM * DD * sizeof(f16);   // 128 MiB
    f16* h0 = (f16*)ws;
    f16* h1 = (f16*)(ws + hbytes);
    char* scratch = ws + 2 * hbytes;
    float* carry = (float*)scratch;                         // 8 MiB, scan phase only
    f16*   wf    = (f16*)scratch;                           // 8 MiB, reused after scan
    float* pbuf  = (float*)h0;                              // 2 MiB, layer-4 partials
                                                            // (h0 free during layer 4)

    // 1. scan (chunked, 3 passes)
    scan_pass1<<<(NCHUNK * BD) / 256, 256, 0, stream>>>(x, Alog, h0, carry);
    scan_pass2<<<BD / 256, 256, 0, stream>>>(Alog, carry);
    scan_pass3<<<(NCHUNK * BD) / 256, 256, 0, stream>>>(Alog, carry, h0);

    // 2. weights fp32 -> fp16 (reuses carry region; stream-ordered after pass3)
    cvt_w<<<(NLAYERS * DD * DD / 4) / 256, 256, 0, stream>>>(Wls, wf, NLAYERS * DD * DD);

    // 3. four layers, ping-pong; layer 4 fuses the head dot-product
    dim3 grid((MM / BM) * (NN / BN)), blk(256);
    gemm_tanh<<<grid, blk, 0, stream>>>(h0, wf + 0 * (DD * DD), bls + 0 * DD, h1, nullptr, nullptr);
    gemm_tanh<<<grid, blk, 0, stream>>>(h1, wf + 1 * (DD * DD), bls + 1 * DD, h0, nullptr, nullptr);
    gemm_tanh<<<grid, blk, 0, stream>>>(h0, wf + 2 * (DD * DD), bls + 2 * DD, h1, nullptr, nullptr);
    gemm_tanh<<<grid, blk, 0, stream>>>(h1, wf + 3 * (DD * DD), bls + 3 * DD, nullptr, hw, pbuf);

    // 4. head: sum the 8 per-N-block partials + bias
    head_final<<<MM / 256, 256, 0, stream>>>(pbuf, hb, out);
}